// Round 27
// baseline (136.881 us; speedup 1.0000x reference)
//
#include <hip/hip_runtime.h>
#include <hip/hip_bf16.h>
#include <stdint.h>

// ---------------------------------------------------------------------------
// SelfAttention fused pipeline. FP32 device buffers; bf16 MFMA, fp32 accum.
//   K0: single fused fp32->bf16 convert for x|qkv_w|proj_w (1 launch)
//   K1: qkv GEMM (gload16 dbuf staging, swizzled LDS, LDS-transposed V write,
//       scalar RoPE epilogue, launch_bounds(256,4))
//   K2: flash attention, K-sliced waves; 2-BUFFER staging (32KB LDS) +
//       launch_bounds(256,4) -> 4 blocks/CU (was LDS-capped at 3 with the
//       3-deep pipeline that r23 proved null); K=16 PV as one asm block.
//   K3: proj GEMM (gload16 dbuf staging, swizzled LDS) + bias -> fp32 out
// B=2 N=2048 D=768 H=12 Dh=64.
// ---------------------------------------------------------------------------

typedef unsigned short u16;
typedef __attribute__((ext_vector_type(8))) short s16x8;   // 8 x bf16 (4 VGPRs)
typedef __attribute__((ext_vector_type(4))) short s16x4;   // 4 x bf16 (2 VGPRs)
typedef __attribute__((ext_vector_type(4))) float f32x4;   // MFMA accumulator

#define MFMA16(a, b, c) __builtin_amdgcn_mfma_f32_16x16x32_bf16((a), (b), (c), 0, 0, 0)

__device__ __forceinline__ u16 f2bf(float f) {  // round-to-nearest-even
    uint32_t u = __float_as_uint(f);
    u = u + 0x7fffu + ((u >> 16) & 1u);
    return (u16)(u >> 16);
}
__device__ __forceinline__ uint32_t pk2(float lo, float hi) {
    return (uint32_t)f2bf(lo) | ((uint32_t)f2bf(hi) << 16);
}
// truncating bf16 pack: D = [hi.b3,hi.b2,lo.b3,lo.b2] via one v_perm_b32
__device__ __forceinline__ uint32_t pk2t(float lo, float hi) {
    return __builtin_amdgcn_perm(__float_as_uint(hi), __float_as_uint(lo),
                                 0x07060302u);
}
// raw v_exp_f32 (= 2^x exactly); args here are in [-31, 8] so no range issues
__device__ __forceinline__ float fexp2(float x) { return __builtin_amdgcn_exp2f(x); }

// async global->LDS, 16B/lane; LDS dest = wave-uniform base + lane*16
__device__ __forceinline__ void gload16(const void* g, void* l) {
    __builtin_amdgcn_global_load_lds(
        (const __attribute__((address_space(1))) unsigned int*)g,
        (__attribute__((address_space(3))) unsigned int*)l,
        16, 0, 0);
}

// ---------------------------------------------------------------------------
// K0: fused fp32 -> bf16 convert of the three inputs (one launch).
// ---------------------------------------------------------------------------
__global__ __launch_bounds__(256)
void k_cvt3(const float* __restrict__ s0, const float* __restrict__ s1,
            const float* __restrict__ s2, u16* __restrict__ dst,
            int a, int ab, int tot)
{
    const int i = blockIdx.x * 256 + threadIdx.x;
    if (i >= tot) return;
    const float4* src;
    if (i < a)       src = (const float4*)s0 + i;
    else if (i < ab) src = (const float4*)s1 + (i - a);
    else             src = (const float4*)s2 + (i - ab);
    const float4 v = *src;
    ushort4 o;
    o.x = f2bf(v.x); o.y = f2bf(v.y); o.z = f2bf(v.z); o.w = f2bf(v.w);
    ((ushort4*)dst)[i] = o;
}

// ---------------------------------------------------------------------------
// K1: QKV GEMM (128x128 tile, BK=32) with fused RoPE epilogue.
// grid (32, 18), 256 threads. Double-buffered gload16 staging, chunk-XOR
// swizzle; V written TRANSPOSED vtws[b,h,dh,tok] via padded-LDS transpose.
// Q pre-scaled 0.125*log2e. Blocks pure q (y<6), k (6..11), v (>=12).
// ---------------------------------------------------------------------------
__global__ __launch_bounds__(256, 4)
void k_qkv_rope(const u16* __restrict__ X,     // [4096][768] bf16
                const u16* __restrict__ W,     // [2304][768] bf16
                const float* __restrict__ SIN, // [2048][64] fp32
                const float* __restrict__ COS, // [2048][64] fp32
                u16* __restrict__ qws, u16* __restrict__ kws, u16* __restrict__ vtws)
{
    __shared__ u16 smem[17408];   // As[2]|Bs[2] (32KB) ∪ Vt[128][136] (34KB)
    u16* const As0 = smem;
    u16* const Bs0 = smem + 8192;

    const int t  = threadIdx.x;
    const int l  = t & 63;
    const int w  = t >> 6;
    const int cl = l & 15, gh = l >> 4;
    const int brow = blockIdx.x * 128;
    const int bcol = blockIdx.y * 128;
    const int wr = (w >> 1) * 64;
    const int wc = (w & 1) * 64;

    const int srow = w * 16 + (l >> 2);
    const int scol = (((l & 3) ^ ((l >> 3) & 3)) * 8);
    const u16* gA = X + (size_t)(brow + srow) * 768 + scol;
    const u16* gB = W + (size_t)(bcol + srow) * 768 + scol;

    const int csw = ((cl >> 1) & 3);

    f32x4 acc[4][4] = {};

    gload16(gA,            As0 + w * 512);
    gload16(gA + 64 * 768, As0 + 2048 + w * 512);
    gload16(gB,            Bs0 + w * 512);
    gload16(gB + 64 * 768, Bs0 + 2048 + w * 512);
    __syncthreads();

    for (int kt = 0; kt < 24; ++kt) {
        const int cur = kt & 1;
        if (kt + 1 < 24) {
            const int k0 = (kt + 1) * 32;
            u16* An = As0 + (cur ^ 1) * 4096;
            u16* Bn = Bs0 + (cur ^ 1) * 4096;
            gload16(gA + k0,            An + w * 512);
            gload16(gA + k0 + 64 * 768, An + 2048 + w * 512);
            gload16(gB + k0,            Bn + w * 512);
            gload16(gB + k0 + 64 * 768, Bn + 2048 + w * 512);
        }
        const char* Ac = (const char*)(As0 + cur * 4096);
        const char* Bc = (const char*)(Bs0 + cur * 4096);
        s16x8 af[4], bv[4];
        #pragma unroll
        for (int m = 0; m < 4; ++m) {
            const int row = wr + m * 16 + cl;
            af[m] = *(const s16x8*)(Ac + row * 64 + ((gh ^ csw) << 4));
        }
        #pragma unroll
        for (int n = 0; n < 4; ++n) {
            const int row = wc + n * 16 + cl;
            bv[n] = *(const s16x8*)(Bc + row * 64 + ((gh ^ csw) << 4));
        }
        #pragma unroll
        for (int m = 0; m < 4; ++m)
            #pragma unroll
            for (int n = 0; n < 4; ++n)
                acc[m][n] = MFMA16(af[m], bv[n], acc[m][n]);
        __syncthreads();
    }

    if (blockIdx.y >= 12) {
        // ---- V path: LDS transpose then coalesced 128B-chunk stores ----
        u16* const Vt = smem;   // [128 cols][136] u16, stride 272B
        #pragma unroll
        for (int m = 0; m < 4; ++m)
            #pragma unroll
            for (int jj = 0; jj < 4; ++jj) {
                const int rowl = wr + m * 16 + gh * 4 + jj;   // tok-local
                #pragma unroll
                for (int n = 0; n < 4; ++n)
                    Vt[(wc + n * 16 + cl) * 136 + rowl] = f2bf(acc[m][n][jj]);
            }
        __syncthreads();
        const int dhcol = t >> 1;                 // 0..127
        const int c     = t & 1;                  // tok half
        const int gcol  = bcol + dhcol;
        const int h     = (gcol >> 6) - 24;
        const int dh    = gcol & 63;
        const int b     = brow >> 11;
        const int tok0  = (brow & 2047) + c * 64;
        u16* dst = vtws + ((size_t)(b * 12 + h) * 64 + dh) * 2048 + tok0;
        const uint4* src = (const uint4*)((const char*)Vt + dhcol * 272 + c * 128);
        #pragma unroll
        for (int j = 0; j < 8; ++j)
            ((uint4*)dst)[j] = src[j];
    } else {
        // ---- q/k path with RoPE (scalar epilogue, r23 proven) ----
        const int seg   = (bcol + wc) >> 6;
        const int which = seg / 12;           // 0:q 1:k
        const int h     = seg % 12;
        const float qscl = (which == 0) ? 0.1803368801111244f : 1.0f;
        u16* outp = (which == 0) ? qws : kws;

        #pragma unroll
        for (int m = 0; m < 4; ++m) {
            #pragma unroll
            for (int jj = 0; jj < 4; ++jj) {
                const int row = brow + wr + m * 16 + gh * 4 + jj;
                const int b   = row >> 11;
                const int tok = row & 2047;
                u16* orow = outp + ((size_t)(b * 12 + h) * 2048 + tok) * 64;
                const float* srow2 = SIN + tok * 64;
                const float* crow2 = COS + tok * 64;
                #pragma unroll
                for (int n = 0; n < 4; ++n) {
                    const int dh = n * 16 + cl;
                    const float v = acc[m][n][jj];
                    const float partner = (n < 2) ? -acc[m][n + 2][jj] : acc[m][n - 2][jj];
                    orow[dh] = f2bf((v * crow2[dh] + partner * srow2[dh]) * qscl);
                }
            }
        }
    }
}

// ---------------------------------------------------------------------------
// K2: flash attention, K-sliced waves, 2-BUFFER staging, 4 blocks/CU.
// grid 768 x 256. Block = 64 q-rows; wave w = all 64 q x k-slice [w*16,+16).
// Tile kt+1 staged (gload16) during tile kt; per-tile __syncthreads() drains
// vmcnt (r23 proved counted-vmcnt null, so the drain costs nothing) -- the
// 32KB LDS footprint is what buys the 4th co-resident block (vs 48KB at 3).
// Fixed-base softmax (C-init=-12, exp2, truncating pack) -> K=16 PV as ONE
// asm block (single s_nop hazard guard). Linear end-combine via LDS.
// ---------------------------------------------------------------------------
__global__ __launch_bounds__(256, 4)
void k_attn(const u16* __restrict__ Qg, const u16* __restrict__ Kg,
            const u16* __restrict__ VTg, u16* __restrict__ Og)
{
    __shared__ u16 Ks[2][64 * 64];   // [buf][krow][64 cols], swizzled, 16KB
    __shared__ u16 Vs[2][64 * 64];   // [buf][dh  ][64 toks], swizzled, 16KB

    const int t  = threadIdx.x;
    const int l  = t & 63;
    const int w  = t >> 6;                      // 0..3 = k-slice
    const int cl = l & 15, gh = l >> 4;

    // bijective swizzle: XCD (= i%8, assumed) owns 3 consecutive heads
    const int i  = blockIdx.x;                  // 0..767
    const int bh = (i & 7) * 3 + ((i >> 3) % 3);
    const int qt = i / 24;                      // 0..31
    const int qb = qt * 64;                     // block's 64 q rows

    const u16* Q  = Qg  + (size_t)bh * 2048 * 64;
    const char* Kb  = (const char*)(Kg  + (size_t)bh * 2048 * 64);
    const char* VTb = (const char*)(VTg + (size_t)bh * 64 * 2048);

    // Q B-fragments for all 4 q-tiles: col q = qb+m*16+cl, rows dh=ks*32+gh*8+j
    s16x8 qf[4][2];
    #pragma unroll
    for (int m = 0; m < 4; ++m)
        #pragma unroll
        for (int ks = 0; ks < 2; ++ks)
            qf[m][ks] = *(const s16x8*)(Q + (((qb + m * 16 + cl) << 6) + ks * 32 + gh * 8));

    f32x4 o[4][4] = {};    // partial O^T over k-slice w: [n][m]
    float lrun[4] = {};    // partial l over k-slice w, per q-tile m

    // staging geometry: segment s covers LDS bytes [s*1024, s*1024+1024);
    // lane covers row = s*8 + (l>>3), dest colbyte = (l&7)*16,
    // source colbyte = dest ^ ((row&7)<<4)  (pre-swizzled source)
    const int srow8 = l >> 3;
    const int scolb = (((l & 7) ^ srow8) << 4);
    // fragment read swizzle: byte col ^ ((row&7)<<4), row bits from cl
    const int rsw = (cl & 7) << 4;

// stage tile T into buffers KB/VB (each wave: 2 segs K + 2 segs V)
#define STAGE(T, KB, VB)                                                      \
    {                                                                         \
        const int nb_ = (T) * 64;                                             \
        _Pragma("unroll")                                                     \
        for (int c = 0; c < 2; ++c) {                                         \
            const int s = c * 4 + w;                                          \
            const int grow = s * 8 + srow8;                                   \
            gload16(Kb  + (nb_ + grow) * 128 + scolb,    &(KB)[s * 512]);     \
            gload16(VTb + grow * 4096 + nb_ * 2 + scolb, &(VB)[s * 512]);     \
        }                                                                     \
    }

    // ---- prologue: stage tile 0 into buf 0 ----
    STAGE(0, Ks[0], Vs[0])
    __syncthreads();   // vmcnt(0) drained by compiler before barrier

    for (int kt = 0; kt < 32; ++kt) {
        const int cur = kt & 1;

        // ---- stage tile kt+1 into the other buffer (async) ----
        if (kt + 1 < 32) {
            STAGE(kt + 1, Ks[cur ^ 1], Vs[cur ^ 1])
        }

        // ---- ds_read: K slice rows [w*16,+16) (2 b128), V k-slice (4 b64) ----
        const char* kl = (const char*)Ks[cur];
        const char* vl = (const char*)Vs[cur];
        s16x8 kf[2];
        s16x4 vf[4];
        #pragma unroll
        for (int ks = 0; ks < 2; ++ks)
            kf[ks] = *(const s16x8*)(kl + (w * 16 + cl) * 128 + ((ks * 64 + gh * 16) ^ rsw));
        #pragma unroll
        for (int n = 0; n < 4; ++n)
            vf[n] = *(const s16x4*)(vl + (n * 16 + cl) * 128 + ((w * 32 + gh * 8) ^ rsw));

        // ---- S^T - 12 for k-slice w, all 4 q-tiles ----
        f32x4 st[4];
        #pragma unroll
        for (int m = 0; m < 4; ++m)
            #pragma unroll
            for (int jj = 0; jj < 4; ++jj)
                st[m][jj] = -12.f;
        #pragma unroll
        for (int m = 0; m < 4; ++m)
            #pragma unroll
            for (int ks = 0; ks < 2; ++ks)
                st[m] = MFMA16(kf[ks], qf[m][ks], st[m]);

        // ---- fixed-base softmax: P = 2^(s-12); packs ARE K=16 B-frags ----
        union { uint32_t u[2]; s16x4 v; } pd[4];
        #pragma unroll
        for (int m = 0; m < 4; ++m) {
            const float p0 = fexp2(st[m][0]);
            const float p1 = fexp2(st[m][1]);
            const float p2 = fexp2(st[m][2]);
            const float p3 = fexp2(st[m][3]);
            lrun[m] += (p0 + p1) + (p2 + p3);
            pd[m].u[0] = pk2t(p0, p1);
            pd[m].u[1] = pk2t(p2, p3);
        }

        // ---- PV: one asm block, single hazard nop, 16 K=16 MFMAs ----
        asm volatile(
            "s_nop 3\n\t"
            "v_mfma_f32_16x16x16_bf16 %0, %16, %20, %0\n\t"
            "v_mfma_f32_16x16x16_bf16 %1, %16, %21, %1\n\t"
            "v_mfma_f32_16x16x16_bf16 %2, %16, %22, %2\n\t"
            "v_mfma_f32_16x16x16_bf16 %3, %16, %23, %3\n\t"
            "v_mfma_f32_16x16x16_bf16 %4, %17, %20, %4\n\t"
            "v_mfma_f32_16x16x16_bf16 %5, %17, %21, %5\n\t"
            "v_mfma_f32_16x16x16_bf16 %6, %17, %22, %6\n\t"
            "v_mfma_f32_16x16x16_bf16 %7, %17, %23, %7\n\t"
            "v_mfma_f32_16x16x16_bf16 %8, %18, %20, %8\n\t"
            "v_mfma_f32_16x16x16_bf16 %9, %18, %21, %9\n\t"
            "v_mfma_f32_16x16x16_bf16 %10, %18, %22, %10\n\t"
            "v_mfma_f32_16x16x16_bf16 %11, %18, %23, %11\n\t"
            "v_mfma_f32_16x16x16_bf16 %12, %19, %20, %12\n\t"
            "v_mfma_f32_16x16x16_bf16 %13, %19, %21, %13\n\t"
            "v_mfma_f32_16x16x16_bf16 %14, %19, %22, %14\n\t"
            "v_mfma_f32_16x16x16_bf16 %15, %19, %23, %15"
            : "+v"(o[0][0]), "+v"(o[0][1]), "+v"(o[0][2]), "+v"(o[0][3]),
              "+v"(o[1][0]), "+v"(o[1][1]), "+v"(o[1][2]), "+v"(o[1][3]),
              "+v"(o[2][0]), "+v"(o[2][1]), "+v"(o[2][2]), "+v"(o[2][3]),
              "+v"(o[3][0]), "+v"(o[3][1]), "+v"(o[3][2]), "+v"(o[3][3])
            : "v"(vf[0]), "v"(vf[1]), "v"(vf[2]), "v"(vf[3]),
              "v"(pd[0].v), "v"(pd[1].v), "v"(pd[2].v), "v"(pd[3].v));

        __syncthreads();   // staging of kt+1 complete; buf[cur] free for kt+2
    }
#undef STAGE

    // ---- end combine: linear sum of per-wave (O, l) partials via LDS ----
    // OL[n][w][lane] f32x4 (16KB, aliases Ks); ML[m][w][lane] float (4KB, Vs)
    f32x4* OL = (f32x4*)&Ks[0][0];
    float*  ML = (float*)&Vs[0][0];
    const int b = bh / 12, h = bh % 12;

    #pragma unroll
    for (int m = 0; m < 4; ++m) {
        float lr = lrun[m];
        lr += __shfl_xor(lr, 16);   // reduce over gh replicas (k sub-groups)
        lr += __shfl_xor(lr, 32);
        ML[(m * 4 + w) * 64 + l] = lr;
    }

    #pragma unroll
    for (int m = 0; m < 4; ++m) {
        __syncthreads();   // ML visible (m=0); previous round's reads done
        #pragma unroll
        for (int n = 0; n < 4; ++n)
            OL[(n * 4 + w) * 64 + l] = o[n][m];
        __syncthreads();
        // wave w merges dh-tile n = w
        f32x4 oacc = OL[(w * 4 + 0) * 64 + l];
        oacc += OL[(w * 4 + 1) * 64 + l];
        oacc += OL[(w * 4 + 2) * 64 + l];
        oacc += OL[(w * 4 + 3) * 64 + l];
        const float lt = ML[(m * 4 + 0) * 64 + l] + ML[(m * 4 + 1) * 64 + l]
                       + ML[(m * 4 + 2) * 64 + l] + ML[(m * 4 + 3) * 64 + l];
        const float inv = 1.0f / lt;
        const int tok = qb + m * 16 + cl;
        u16* orow = Og + ((size_t)(b * 2048 + tok)) * 768 + h * 64 + w * 16 + gh * 4;
        uint2 pkv;
        pkv.x = pk2(oacc[0] * inv, oacc[1] * inv);
        pkv.y = pk2(oacc[2] * inv, oacc[3] * inv);
        *(uint2*)orow = pkv;
    }
}

// ---------------------------------------------------------------------------
// K3: output projection + bias (fp32 out). grid (32, 6).
// ---------------------------------------------------------------------------
__global__ __launch_bounds__(256, 2)
void k_proj(const u16* __restrict__ A,      // [4096][768] bf16
            const u16* __restrict__ W,      // [768][768] bf16
            const float* __restrict__ BIAS, // [768] fp32
            float* __restrict__ OUT)        // [4096][768] fp32
{
    __shared__ u16 smem[16384];   // As[2]|Bs[2], 32KB
    u16* const As0 = smem;
    u16* const Bs0 = smem + 8192;

    const int t  = threadIdx.x;
    const int l  = t & 63;
    const int w  = t >> 6;
    const int cl = l & 15, gh = l >> 4;
    const int brow = blockIdx.x * 128;
    const int bcol = blockIdx.y * 128;
    const int wr = (w >> 1) * 64;
    const int wc = (w & 1) * 64;

    const int srow = w * 16 + (l >> 2);
    const int scol = (((l & 3) ^ ((l >> 3) & 3)) * 8);
    const u16* gA = A + (size_t)(brow + srow) * 768 + scol;
    const u16* gB = W + (size_t)(bcol + srow) * 768 + scol;
    const int csw = ((cl >> 1) & 3);

    f32x4 acc[4][4] = {};

    gload16(gA,            As0 + w * 512);
    gload16(gA + 64 * 768, As0 + 2048 + w * 512);
    gload16(gB,            Bs0 + w * 512);
    gload16(gB + 64 * 768, Bs0 + 2048 + w * 512);
    __syncthreads();

    for (int kt = 0; kt < 24; ++kt) {
        const int cur = kt & 1;
        if (kt + 1 < 24) {
            const int k0 = (kt + 1) * 32;
            u16* An = As0 + (cur ^ 1) * 4096;
            u16* Bn = Bs0 + (cur ^ 1) * 4096;
            gload16(gA + k0,            An + w * 512);
            gload16(gA + k0 + 64 * 768, An + 2048 + w * 512);
            gload16(gB + k0,            Bn + w * 512);
            gload16(gB + k0 + 64 * 768, Bn + 2048 + w * 512);
        }
        const char* Ac = (const char*)(As0 + cur * 4096);
        const char* Bc = (const char*)(Bs0 + cur * 4096);
        s16x8 af[4], bv[4];
        #pragma unroll
        for (int m = 0; m < 4; ++m) {
            const int row = wr + m * 16 + cl;
            af[m] = *(const s16x8*)(Ac + row * 64 + ((gh ^ csw) << 4));
        }
        #pragma unroll
        for (int n = 0; n < 4; ++n) {
            const int row = wc + n * 16 + cl;
            bv[n] = *(const s16x8*)(Bc + row * 64 + ((gh ^ csw) << 4));
        }
        #pragma unroll
        for (int m = 0; m < 4; ++m)
            #pragma unroll
            for (int n = 0; n < 4; ++n)
                acc[m][n] = MFMA16(af[m], bv[n], acc[m][n]);
        __syncthreads();
    }

    #pragma unroll
    for (int m = 0; m < 4; ++m) {
        #pragma unroll
        for (int jj = 0; jj < 4; ++jj) {
            const int row = brow + wr + m * 16 + gh * 4 + jj;
            #pragma unroll
            for (int n = 0; n < 4; ++n) {
                const int col = bcol + wc + n * 16 + cl;
                OUT[(size_t)row * 768 + col] = acc[m][n][jj] + BIAS[col];
            }
        }
    }
}

// ---------------------------------------------------------------------------
extern "C" void kernel_launch(void* const* d_in, const int* in_sizes, int n_in,
                              void* d_out, int out_size, void* d_ws, size_t ws_size,
                              hipStream_t stream)
{
    const float* x     = (const float*)d_in[0];
    const float* sinp  = (const float*)d_in[1];
    const float* cosp  = (const float*)d_in[2];
    const float* qkv_w = (const float*)d_in[3];
    const float* projw = (const float*)d_in[4];
    const float* projb = (const float*)d_in[5];
    float* out = (float*)d_out;

    const size_t N_X  = (size_t)4096 * 768;
    const size_t N_WQ = (size_t)2304 * 768;
    const size_t N_WP = (size_t)768 * 768;
    const size_t SEG  = (size_t)2 * 12 * 2048 * 64;

    u16* xbf   = (u16*)d_ws;
    u16* wqkv  = xbf + N_X;
    u16* wproj = wqkv + N_WQ;
    u16* qws   = wproj + N_WP;
    u16* kws   = qws + SEG;
    u16* vtws  = kws + SEG;   // transposed V [B,H,64,2048]
    u16* aws   = vtws + SEG;

    const int a   = (int)(N_X / 4);
    const int ab  = (int)((N_X + N_WQ) / 4);
    const int tot = (int)((N_X + N_WQ + N_WP) / 4);
    k_cvt3<<<(tot + 255) / 256, 256, 0, stream>>>(x, qkv_w, projw, xbf, a, ab, tot);

    k_qkv_rope<<<dim3(32, 18), 256, 0, stream>>>(xbf, wqkv, sinp, cosp, qws, kws, vtws);
    k_attn    <<<768, 256, 0, stream>>>(qws, kws, vtws, aws);
    k_proj    <<<dim3(32, 6),  256, 0, stream>>>(aws, wproj, projb, out);
}

// Round 28
// 91.193 us; speedup vs baseline: 1.5010x; 1.5010x over previous
//
#include <hip/hip_runtime.h>
#include <hip/hip_bf16.h>
#include <stdint.h>

// ---------------------------------------------------------------------------
// SelfAttention fused pipeline. FP32 device buffers; bf16 MFMA, fp32 accum.
//   K0: single fused fp32->bf16 convert for x|qkv_w|proj_w (1 launch)
//   K1: qkv GEMM (gload16 dbuf staging, swizzled LDS, LDS-transposed V write,
//       scalar RoPE epilogue, launch_bounds(256,4))
//   K2: flash attention (r26 BANKED BEST: K-sliced waves, counted-vmcnt
//       3-deep pipeline at (256,3) -- (256,4) spilled in r27 (VGPR 64,
//       33MB scratch traffic) -- fixed-base exp2, K=16 PV as one asm block)
//   K3: proj GEMM (gload16 dbuf staging, swizzled LDS) + bias -> fp32 out
// B=2 N=2048 D=768 H=12 Dh=64.
// ---------------------------------------------------------------------------

typedef unsigned short u16;
typedef __attribute__((ext_vector_type(8))) short s16x8;   // 8 x bf16 (4 VGPRs)
typedef __attribute__((ext_vector_type(4))) short s16x4;   // 4 x bf16 (2 VGPRs)
typedef __attribute__((ext_vector_type(4))) float f32x4;   // MFMA accumulator

#define MFMA16(a, b, c) __builtin_amdgcn_mfma_f32_16x16x32_bf16((a), (b), (c), 0, 0, 0)

__device__ __forceinline__ u16 f2bf(float f) {  // round-to-nearest-even
    uint32_t u = __float_as_uint(f);
    u = u + 0x7fffu + ((u >> 16) & 1u);
    return (u16)(u >> 16);
}
__device__ __forceinline__ uint32_t pk2(float lo, float hi) {
    return (uint32_t)f2bf(lo) | ((uint32_t)f2bf(hi) << 16);
}
// truncating bf16 pack: D = [hi.b3,hi.b2,lo.b3,lo.b2] via one v_perm_b32
__device__ __forceinline__ uint32_t pk2t(float lo, float hi) {
    return __builtin_amdgcn_perm(__float_as_uint(hi), __float_as_uint(lo),
                                 0x07060302u);
}
// raw v_exp_f32 (= 2^x exactly); args here are in [-31, 8] so no range issues
__device__ __forceinline__ float fexp2(float x) { return __builtin_amdgcn_exp2f(x); }

// async global->LDS, 16B/lane; LDS dest = wave-uniform base + lane*16
__device__ __forceinline__ void gload16(const void* g, void* l) {
    __builtin_amdgcn_global_load_lds(
        (const __attribute__((address_space(1))) unsigned int*)g,
        (__attribute__((address_space(3))) unsigned int*)l,
        16, 0, 0);
}

// ---------------------------------------------------------------------------
// K0: fused fp32 -> bf16 convert of the three inputs (one launch).
// ---------------------------------------------------------------------------
__global__ __launch_bounds__(256)
void k_cvt3(const float* __restrict__ s0, const float* __restrict__ s1,
            const float* __restrict__ s2, u16* __restrict__ dst,
            int a, int ab, int tot)
{
    const int i = blockIdx.x * 256 + threadIdx.x;
    if (i >= tot) return;
    const float4* src;
    if (i < a)       src = (const float4*)s0 + i;
    else if (i < ab) src = (const float4*)s1 + (i - a);
    else             src = (const float4*)s2 + (i - ab);
    const float4 v = *src;
    ushort4 o;
    o.x = f2bf(v.x); o.y = f2bf(v.y); o.z = f2bf(v.z); o.w = f2bf(v.w);
    ((ushort4*)dst)[i] = o;
}

// ---------------------------------------------------------------------------
// K1: QKV GEMM (128x128 tile, BK=32) with fused RoPE epilogue.
// grid (32, 18), 256 threads, 4 blocks/CU. Double-buffered gload16 staging,
// chunk-XOR swizzle; V written TRANSPOSED vtws[b,h,dh,tok] via padded-LDS
// transpose. Q pre-scaled 0.125*log2e. Blocks pure q (y<6), k (6..11), v>=12.
// ---------------------------------------------------------------------------
__global__ __launch_bounds__(256, 4)
void k_qkv_rope(const u16* __restrict__ X,     // [4096][768] bf16
                const u16* __restrict__ W,     // [2304][768] bf16
                const float* __restrict__ SIN, // [2048][64] fp32
                const float* __restrict__ COS, // [2048][64] fp32
                u16* __restrict__ qws, u16* __restrict__ kws, u16* __restrict__ vtws)
{
    __shared__ u16 smem[17408];   // As[2]|Bs[2] (32KB) ∪ Vt[128][136] (34KB)
    u16* const As0 = smem;
    u16* const Bs0 = smem + 8192;

    const int t  = threadIdx.x;
    const int l  = t & 63;
    const int w  = t >> 6;
    const int cl = l & 15, gh = l >> 4;
    const int brow = blockIdx.x * 128;
    const int bcol = blockIdx.y * 128;
    const int wr = (w >> 1) * 64;
    const int wc = (w & 1) * 64;

    const int srow = w * 16 + (l >> 2);
    const int scol = (((l & 3) ^ ((l >> 3) & 3)) * 8);
    const u16* gA = X + (size_t)(brow + srow) * 768 + scol;
    const u16* gB = W + (size_t)(bcol + srow) * 768 + scol;

    const int csw = ((cl >> 1) & 3);

    f32x4 acc[4][4] = {};

    gload16(gA,            As0 + w * 512);
    gload16(gA + 64 * 768, As0 + 2048 + w * 512);
    gload16(gB,            Bs0 + w * 512);
    gload16(gB + 64 * 768, Bs0 + 2048 + w * 512);
    __syncthreads();

    for (int kt = 0; kt < 24; ++kt) {
        const int cur = kt & 1;
        if (kt + 1 < 24) {
            const int k0 = (kt + 1) * 32;
            u16* An = As0 + (cur ^ 1) * 4096;
            u16* Bn = Bs0 + (cur ^ 1) * 4096;
            gload16(gA + k0,            An + w * 512);
            gload16(gA + k0 + 64 * 768, An + 2048 + w * 512);
            gload16(gB + k0,            Bn + w * 512);
            gload16(gB + k0 + 64 * 768, Bn + 2048 + w * 512);
        }
        const char* Ac = (const char*)(As0 + cur * 4096);
        const char* Bc = (const char*)(Bs0 + cur * 4096);
        s16x8 af[4], bv[4];
        #pragma unroll
        for (int m = 0; m < 4; ++m) {
            const int row = wr + m * 16 + cl;
            af[m] = *(const s16x8*)(Ac + row * 64 + ((gh ^ csw) << 4));
        }
        #pragma unroll
        for (int n = 0; n < 4; ++n) {
            const int row = wc + n * 16 + cl;
            bv[n] = *(const s16x8*)(Bc + row * 64 + ((gh ^ csw) << 4));
        }
        #pragma unroll
        for (int m = 0; m < 4; ++m)
            #pragma unroll
            for (int n = 0; n < 4; ++n)
                acc[m][n] = MFMA16(af[m], bv[n], acc[m][n]);
        __syncthreads();
    }

    if (blockIdx.y >= 12) {
        // ---- V path: LDS transpose then coalesced 128B-chunk stores ----
        u16* const Vt = smem;   // [128 cols][136] u16, stride 272B
        #pragma unroll
        for (int m = 0; m < 4; ++m)
            #pragma unroll
            for (int jj = 0; jj < 4; ++jj) {
                const int rowl = wr + m * 16 + gh * 4 + jj;   // tok-local
                #pragma unroll
                for (int n = 0; n < 4; ++n)
                    Vt[(wc + n * 16 + cl) * 136 + rowl] = f2bf(acc[m][n][jj]);
            }
        __syncthreads();
        const int dhcol = t >> 1;                 // 0..127
        const int c     = t & 1;                  // tok half
        const int gcol  = bcol + dhcol;
        const int h     = (gcol >> 6) - 24;
        const int dh    = gcol & 63;
        const int b     = brow >> 11;
        const int tok0  = (brow & 2047) + c * 64;
        u16* dst = vtws + ((size_t)(b * 12 + h) * 64 + dh) * 2048 + tok0;
        const uint4* src = (const uint4*)((const char*)Vt + dhcol * 272 + c * 128);
        #pragma unroll
        for (int j = 0; j < 8; ++j)
            ((uint4*)dst)[j] = src[j];
    } else {
        // ---- q/k path with RoPE (scalar epilogue, r23 proven) ----
        const int seg   = (bcol + wc) >> 6;
        const int which = seg / 12;           // 0:q 1:k
        const int h     = seg % 12;
        const float qscl = (which == 0) ? 0.1803368801111244f : 1.0f;
        u16* outp = (which == 0) ? qws : kws;

        #pragma unroll
        for (int m = 0; m < 4; ++m) {
            #pragma unroll
            for (int jj = 0; jj < 4; ++jj) {
                const int row = brow + wr + m * 16 + gh * 4 + jj;
                const int b   = row >> 11;
                const int tok = row & 2047;
                u16* orow = outp + ((size_t)(b * 12 + h) * 2048 + tok) * 64;
                const float* srow2 = SIN + tok * 64;
                const float* crow2 = COS + tok * 64;
                #pragma unroll
                for (int n = 0; n < 4; ++n) {
                    const int dh = n * 16 + cl;
                    const float v = acc[m][n][jj];
                    const float partner = (n < 2) ? -acc[m][n + 2][jj] : acc[m][n - 2][jj];
                    orow[dh] = f2bf((v * crow2[dh] + partner * srow2[dh]) * qscl);
                }
            }
        }
    }
}

// ---------------------------------------------------------------------------
// K2: flash attention, K-sliced waves + counted-vmcnt 3-deep pipeline (r26).
// PV stage is ONE asm block: single s_nop 3 then 16 v_mfma_f32_16x16x16_bf16.
// (256,3): forcing 4 blocks/CU spills (r27: VGPR 64, 33MB scratch traffic).
// ---------------------------------------------------------------------------
__global__ __launch_bounds__(256, 3)
void k_attn(const u16* __restrict__ Qg, const u16* __restrict__ Kg,
            const u16* __restrict__ VTg, u16* __restrict__ Og)
{
    __shared__ u16 Ks[3][64 * 64];   // [buf][krow][64 cols], swizzled, 24KB
    __shared__ u16 Vs[3][64 * 64];   // [buf][dh  ][64 toks], swizzled, 24KB

    const int t  = threadIdx.x;
    const int l  = t & 63;
    const int w  = t >> 6;                      // 0..3 = k-slice
    const int cl = l & 15, gh = l >> 4;

    // bijective swizzle: XCD (= i%8, assumed) owns 3 consecutive heads
    const int i  = blockIdx.x;                  // 0..767
    const int bh = (i & 7) * 3 + ((i >> 3) % 3);
    const int qt = i / 24;                      // 0..31
    const int qb = qt * 64;                     // block's 64 q rows

    const u16* Q  = Qg  + (size_t)bh * 2048 * 64;
    const char* Kb  = (const char*)(Kg  + (size_t)bh * 2048 * 64);
    const char* VTb = (const char*)(VTg + (size_t)bh * 64 * 2048);

    // Q B-fragments for all 4 q-tiles: col q = qb+m*16+cl, rows dh=ks*32+gh*8+j
    s16x8 qf[4][2];
    #pragma unroll
    for (int m = 0; m < 4; ++m)
        #pragma unroll
        for (int ks = 0; ks < 2; ++ks)
            qf[m][ks] = *(const s16x8*)(Q + (((qb + m * 16 + cl) << 6) + ks * 32 + gh * 8));

    f32x4 o[4][4] = {};    // partial O^T over k-slice w: [n][m]
    float lrun[4] = {};    // partial l over k-slice w, per q-tile m

    // staging geometry: segment s covers LDS bytes [s*1024, s*1024+1024);
    // lane covers row = s*8 + (l>>3), dest colbyte = (l&7)*16,
    // source colbyte = dest ^ ((row&7)<<4)  (pre-swizzled source)
    const int srow8 = l >> 3;
    const int scolb = (((l & 7) ^ srow8) << 4);
    // fragment read swizzle: byte col ^ ((row&7)<<4), row bits from cl
    const int rsw = (cl & 7) << 4;

// stage tile T into buffers KB/VB (each wave: 2 segs K + 2 segs V)
#define STAGE(T, KB, VB)                                                      \
    {                                                                         \
        const int nb_ = (T) * 64;                                             \
        _Pragma("unroll")                                                     \
        for (int c = 0; c < 2; ++c) {                                         \
            const int s = c * 4 + w;                                          \
            const int grow = s * 8 + srow8;                                   \
            gload16(Kb  + (nb_ + grow) * 128 + scolb,    &(KB)[s * 512]);     \
            gload16(VTb + grow * 4096 + nb_ * 2 + scolb, &(VB)[s * 512]);     \
        }                                                                     \
    }

    // ---- prologue: stage tiles 0 and 1; wait tile 0 (leave tile 1) ----
    STAGE(0, Ks[0], Vs[0])
    STAGE(1, Ks[1], Vs[1])
    asm volatile("s_waitcnt vmcnt(4)" ::: "memory");
    __builtin_amdgcn_s_barrier();

    int ci = 0;   // compute buffer index = kt % 3
    for (int kt = 0; kt < 32; ++kt) {
        // ---- stage tile kt+2 into buffer (kt+2)%3 ----
        if (kt + 2 < 32) {
            const int ii = (ci + 2 >= 3) ? ci - 1 : ci + 2;
            STAGE(kt + 2, Ks[ii], Vs[ii])
        }

        // ---- ds_read: K slice rows [w*16,+16) (2 b128), V k-slice (4 b64) ----
        const char* kl = (const char*)Ks[ci];
        const char* vl = (const char*)Vs[ci];
        s16x8 kf[2];
        s16x4 vf[4];
        #pragma unroll
        for (int ks = 0; ks < 2; ++ks)
            kf[ks] = *(const s16x8*)(kl + (w * 16 + cl) * 128 + ((ks * 64 + gh * 16) ^ rsw));
        #pragma unroll
        for (int n = 0; n < 4; ++n)
            vf[n] = *(const s16x4*)(vl + (n * 16 + cl) * 128 + ((w * 32 + gh * 8) ^ rsw));

        // ---- S^T - 12 for k-slice w, all 4 q-tiles ----
        f32x4 st[4];
        #pragma unroll
        for (int m = 0; m < 4; ++m)
            #pragma unroll
            for (int jj = 0; jj < 4; ++jj)
                st[m][jj] = -12.f;
        #pragma unroll
        for (int m = 0; m < 4; ++m)
            #pragma unroll
            for (int ks = 0; ks < 2; ++ks)
                st[m] = MFMA16(kf[ks], qf[m][ks], st[m]);

        // ---- fixed-base softmax: P = 2^(s-12); packs ARE K=16 B-frags ----
        union { uint32_t u[2]; s16x4 v; } pd[4];
        #pragma unroll
        for (int m = 0; m < 4; ++m) {
            const float p0 = fexp2(st[m][0]);
            const float p1 = fexp2(st[m][1]);
            const float p2 = fexp2(st[m][2]);
            const float p3 = fexp2(st[m][3]);
            lrun[m] += (p0 + p1) + (p2 + p3);
            pd[m].u[0] = pk2t(p0, p1);
            pd[m].u[1] = pk2t(p2, p3);
        }

        // ---- PV: one asm block, single hazard nop, 16 K=16 MFMAs ----
        asm volatile(
            "s_nop 3\n\t"
            "v_mfma_f32_16x16x16_bf16 %0, %16, %20, %0\n\t"
            "v_mfma_f32_16x16x16_bf16 %1, %16, %21, %1\n\t"
            "v_mfma_f32_16x16x16_bf16 %2, %16, %22, %2\n\t"
            "v_mfma_f32_16x16x16_bf16 %3, %16, %23, %3\n\t"
            "v_mfma_f32_16x16x16_bf16 %4, %17, %20, %4\n\t"
            "v_mfma_f32_16x16x16_bf16 %5, %17, %21, %5\n\t"
            "v_mfma_f32_16x16x16_bf16 %6, %17, %22, %6\n\t"
            "v_mfma_f32_16x16x16_bf16 %7, %17, %23, %7\n\t"
            "v_mfma_f32_16x16x16_bf16 %8, %18, %20, %8\n\t"
            "v_mfma_f32_16x16x16_bf16 %9, %18, %21, %9\n\t"
            "v_mfma_f32_16x16x16_bf16 %10, %18, %22, %10\n\t"
            "v_mfma_f32_16x16x16_bf16 %11, %18, %23, %11\n\t"
            "v_mfma_f32_16x16x16_bf16 %12, %19, %20, %12\n\t"
            "v_mfma_f32_16x16x16_bf16 %13, %19, %21, %13\n\t"
            "v_mfma_f32_16x16x16_bf16 %14, %19, %22, %14\n\t"
            "v_mfma_f32_16x16x16_bf16 %15, %19, %23, %15"
            : "+v"(o[0][0]), "+v"(o[0][1]), "+v"(o[0][2]), "+v"(o[0][3]),
              "+v"(o[1][0]), "+v"(o[1][1]), "+v"(o[1][2]), "+v"(o[1][3]),
              "+v"(o[2][0]), "+v"(o[2][1]), "+v"(o[2][2]), "+v"(o[2][3]),
              "+v"(o[3][0]), "+v"(o[3][1]), "+v"(o[3][2]), "+v"(o[3][3])
            : "v"(vf[0]), "v"(vf[1]), "v"(vf[2]), "v"(vf[3]),
              "v"(pd[0].v), "v"(pd[1].v), "v"(pd[2].v), "v"(pd[3].v));

        // ---- counted fence: tile kt+1 landed; kt+2's 4 loads in flight ----
        if (kt < 30) asm volatile("s_waitcnt vmcnt(4)" ::: "memory");
        else         asm volatile("s_waitcnt vmcnt(0)" ::: "memory");
        __builtin_amdgcn_s_barrier();

        ci = (ci == 2) ? 0 : ci + 1;
    }
#undef STAGE

    // ---- end combine: linear sum of per-wave (O, l) partials via LDS ----
    // OL[n][w][lane] f32x4 (16KB, aliases Ks); ML[m][w][lane] float (4KB, Vs)
    f32x4* OL = (f32x4*)&Ks[0][0];
    float*  ML = (float*)&Vs[0][0];
    const int b = bh / 12, h = bh % 12;

    #pragma unroll
    for (int m = 0; m < 4; ++m) {
        float lr = lrun[m];
        lr += __shfl_xor(lr, 16);   // reduce over gh replicas (k sub-groups)
        lr += __shfl_xor(lr, 32);
        ML[(m * 4 + w) * 64 + l] = lr;
    }

    #pragma unroll
    for (int m = 0; m < 4; ++m) {
        __syncthreads();   // ML visible (m=0); previous round's reads done
        #pragma unroll
        for (int n = 0; n < 4; ++n)
            OL[(n * 4 + w) * 64 + l] = o[n][m];
        __syncthreads();
        // wave w merges dh-tile n = w
        f32x4 oacc = OL[(w * 4 + 0) * 64 + l];
        oacc += OL[(w * 4 + 1) * 64 + l];
        oacc += OL[(w * 4 + 2) * 64 + l];
        oacc += OL[(w * 4 + 3) * 64 + l];
        const float lt = ML[(m * 4 + 0) * 64 + l] + ML[(m * 4 + 1) * 64 + l]
                       + ML[(m * 4 + 2) * 64 + l] + ML[(m * 4 + 3) * 64 + l];
        const float inv = 1.0f / lt;
        const int tok = qb + m * 16 + cl;
        u16* orow = Og + ((size_t)(b * 2048 + tok)) * 768 + h * 64 + w * 16 + gh * 4;
        uint2 pkv;
        pkv.x = pk2(oacc[0] * inv, oacc[1] * inv);
        pkv.y = pk2(oacc[2] * inv, oacc[3] * inv);
        *(uint2*)orow = pkv;
    }
}

// ---------------------------------------------------------------------------
// K3: output projection + bias (fp32 out). grid (32, 6).
// ---------------------------------------------------------------------------
__global__ __launch_bounds__(256, 2)
void k_proj(const u16* __restrict__ A,      // [4096][768] bf16
            const u16* __restrict__ W,      // [768][768] bf16
            const float* __restrict__ BIAS, // [768] fp32
            float* __restrict__ OUT)        // [4096][768] fp32
{
    __shared__ u16 smem[16384];   // As[2]|Bs[2], 32KB
    u16* const As0 = smem;
    u16* const Bs0 = smem + 8192;

    const int t  = threadIdx.x;
    const int l  = t & 63;
    const int w  = t >> 6;
    const int cl = l & 15, gh = l >> 4;
    const int brow = blockIdx.x * 128;
    const int bcol = blockIdx.y * 128;
    const int wr = (w >> 1) * 64;
    const int wc = (w & 1) * 64;

    const int srow = w * 16 + (l >> 2);
    const int scol = (((l & 3) ^ ((l >> 3) & 3)) * 8);
    const u16* gA = A + (size_t)(brow + srow) * 768 + scol;
    const u16* gB = W + (size_t)(bcol + srow) * 768 + scol;
    const int csw = ((cl >> 1) & 3);

    f32x4 acc[4][4] = {};

    gload16(gA,            As0 + w * 512);
    gload16(gA + 64 * 768, As0 + 2048 + w * 512);
    gload16(gB,            Bs0 + w * 512);
    gload16(gB + 64 * 768, Bs0 + 2048 + w * 512);
    __syncthreads();

    for (int kt = 0; kt < 24; ++kt) {
        const int cur = kt & 1;
        if (kt + 1 < 24) {
            const int k0 = (kt + 1) * 32;
            u16* An = As0 + (cur ^ 1) * 4096;
            u16* Bn = Bs0 + (cur ^ 1) * 4096;
            gload16(gA + k0,            An + w * 512);
            gload16(gA + k0 + 64 * 768, An + 2048 + w * 512);
            gload16(gB + k0,            Bn + w * 512);
            gload16(gB + k0 + 64 * 768, Bn + 2048 + w * 512);
        }
        const char* Ac = (const char*)(As0 + cur * 4096);
        const char* Bc = (const char*)(Bs0 + cur * 4096);
        s16x8 af[4], bv[4];
        #pragma unroll
        for (int m = 0; m < 4; ++m) {
            const int row = wr + m * 16 + cl;
            af[m] = *(const s16x8*)(Ac + row * 64 + ((gh ^ csw) << 4));
        }
        #pragma unroll
        for (int n = 0; n < 4; ++n) {
            const int row = wc + n * 16 + cl;
            bv[n] = *(const s16x8*)(Bc + row * 64 + ((gh ^ csw) << 4));
        }
        #pragma unroll
        for (int m = 0; m < 4; ++m)
            #pragma unroll
            for (int n = 0; n < 4; ++n)
                acc[m][n] = MFMA16(af[m], bv[n], acc[m][n]);
        __syncthreads();
    }

    #pragma unroll
    for (int m = 0; m < 4; ++m) {
        #pragma unroll
        for (int jj = 0; jj < 4; ++jj) {
            const int row = brow + wr + m * 16 + gh * 4 + jj;
            #pragma unroll
            for (int n = 0; n < 4; ++n) {
                const int col = bcol + wc + n * 16 + cl;
                OUT[(size_t)row * 768 + col] = acc[m][n][jj] + BIAS[col];
            }
        }
    }
}

// ---------------------------------------------------------------------------
extern "C" void kernel_launch(void* const* d_in, const int* in_sizes, int n_in,
                              void* d_out, int out_size, void* d_ws, size_t ws_size,
                              hipStream_t stream)
{
    const float* x     = (const float*)d_in[0];
    const float* sinp  = (const float*)d_in[1];
    const float* cosp  = (const float*)d_in[2];
    const float* qkv_w = (const float*)d_in[3];
    const float* projw = (const float*)d_in[4];
    const float* projb = (const float*)d_in[5];
    float* out = (float*)d_out;

    const size_t N_X  = (size_t)4096 * 768;
    const size_t N_WQ = (size_t)2304 * 768;
    const size_t N_WP = (size_t)768 * 768;
    const size_t SEG  = (size_t)2 * 12 * 2048 * 64;

    u16* xbf   = (u16*)d_ws;
    u16* wqkv  = xbf + N_X;
    u16* wproj = wqkv + N_WQ;
    u16* qws   = wproj + N_WP;
    u16* kws   = qws + SEG;
    u16* vtws  = kws + SEG;   // transposed V [B,H,64,2048]
    u16* aws   = vtws + SEG;

    const int a   = (int)(N_X / 4);
    const int ab  = (int)((N_X + N_WQ) / 4);
    const int tot = (int)((N_X + N_WQ + N_WP) / 4);
    k_cvt3<<<(tot + 255) / 256, 256, 0, stream>>>(x, qkv_w, projw, xbf, a, ab, tot);

    k_qkv_rope<<<dim3(32, 18), 256, 0, stream>>>(xbf, wqkv, sinp, cosp, qws, kws, vtws);
    k_attn    <<<768, 256, 0, stream>>>(qws, kws, vtws, aws);
    k_proj    <<<dim3(32, 6),  256, 0, stream>>>(aws, wproj, projb, out);
}